// Round 1
// baseline (159.359 us; speedup 1.0000x reference)
//
#include <hip/hip_runtime.h>

typedef float f32x4 __attribute__((ext_vector_type(4)));
typedef __bf16 bf16x8 __attribute__((ext_vector_type(8)));
typedef unsigned short u16;
typedef unsigned int u32;

__device__ __forceinline__ float bf2f(u32 bits16) {
  u32 x = (bits16 & 0xffffu) << 16;
  return __builtin_bit_cast(float, x);
}
__device__ __forceinline__ u16 f2bf(float f) {
  u32 x = __builtin_bit_cast(u32, f);
  x += 0x7fffu + ((x >> 16) & 1u);
  return (u16)(x >> 16);
}
__device__ __forceinline__ void gload16(const void* g, void* l) {
  __builtin_amdgcn_global_load_lds((__attribute__((address_space(1))) void*)g,
                                   (__attribute__((address_space(3))) void*)l,
                                   16, 0, 0);
}

// ---------------- f32 -> bf16 convert (weights) ----------------
__global__ __launch_bounds__(256) void k_tobf16(const float* __restrict__ s,
                                                u16* __restrict__ d, int n) {
  int i = (blockIdx.x * 256 + threadIdx.x) * 4;
  if (i + 3 < n) {
    float4 v = *(const float4*)&s[i];
    u32 a = (u32)f2bf(v.x) | ((u32)f2bf(v.y) << 16);
    u32 b = (u32)f2bf(v.z) | ((u32)f2bf(v.w) << 16);
    *(uint2*)&d[i] = make_uint2(a, b);
  }
}

// cvec[o] = ssm_dw_b @ ssm_out_w[o,:] + ssm_out_b[o]
__global__ __launch_bounds__(256) void k_cvec(const float* __restrict__ Wout,
                                              const float* __restrict__ dwb,
                                              const float* __restrict__ outb,
                                              float* __restrict__ cvec) {
  int o = threadIdx.x;
  float s = outb[o];
  for (int k = 0; k < 512; ++k) s += dwb[k] * Wout[o * 512 + k];
  cvec[o] = s;
}

// ---------------- LN over channels of BCHW + transpose to (n,c) bf16 ----------
__global__ __launch_bounds__(256)
void k_ln2d(const float* __restrict__ x, const float* __restrict__ lw,
            const float* __restrict__ lb, u16* __restrict__ A) {
  __shared__ float ps1[4][64], ps2[4][64];
  __shared__ float mu[64], rsd[64];
  __shared__ float T[64 * 67];
  int tid = threadIdx.x;
  int wv = tid >> 6, p = tid & 63;
  int n0 = blockIdx.x * 64;
  int bb = n0 >> 12;
  int hw0 = n0 & 4095;
  const float* xb = x + ((size_t)bb << 20);
  float s1 = 0.f, s2 = 0.f;
  for (int i = 0; i < 64; ++i) {
    int c = wv * 64 + i;
    float v = xb[((size_t)c << 12) + hw0 + p];
    s1 += v; s2 += v * v;
  }
  ps1[wv][p] = s1; ps2[wv][p] = s2;
  __syncthreads();
  if (tid < 64) {
    float S1 = ps1[0][tid] + ps1[1][tid] + ps1[2][tid] + ps1[3][tid];
    float S2 = ps2[0][tid] + ps2[1][tid] + ps2[2][tid] + ps2[3][tid];
    float m = S1 * (1.f / 256.f);
    float var = S2 * (1.f / 256.f) - m * m;
    mu[tid] = m;
    rsd[tid] = rsqrtf(var + 1e-6f);
  }
  __syncthreads();
  for (int cc = 0; cc < 4; ++cc) {
    #pragma unroll
    for (int i = 0; i < 16; ++i) {
      int cl = i * 4 + wv;
      int c = cc * 64 + cl;
      float v = xb[((size_t)c << 12) + hw0 + p];
      T[cl * 67 + p] = (v - mu[p]) * rsd[p] * lw[c] + lb[c];
    }
    __syncthreads();
    int p2b = tid >> 4, c4 = (tid & 15) * 4;
    #pragma unroll
    for (int i2 = 0; i2 < 4; ++i2) {
      int p2 = p2b + 16 * i2;
      u32 a = (u32)f2bf(T[(c4 + 0) * 67 + p2]) | ((u32)f2bf(T[(c4 + 1) * 67 + p2]) << 16);
      u32 b = (u32)f2bf(T[(c4 + 2) * 67 + p2]) | ((u32)f2bf(T[(c4 + 3) * 67 + p2]) << 16);
      *(uint2*)&A[(size_t)(n0 + p2) * 256 + cc * 64 + c4] = make_uint2(a, b);
    }
    __syncthreads();
  }
}

// ---------------- row LN (contiguous 256) bf16 -> bf16 ----------------
__global__ __launch_bounds__(256)
void k_lnrow(const u16* __restrict__ X, const float* __restrict__ lw,
             const float* __restrict__ lb, u16* __restrict__ O) {
  int tid = threadIdx.x;
  int lane = tid & 63;
  size_t row = (size_t)blockIdx.x * 4 + (tid >> 6);
  const u16* xr = X + row * 256;
  uint2 u = *(const uint2*)&xr[lane * 4];
  float v0 = bf2f(u.x), v1 = bf2f(u.x >> 16), v2 = bf2f(u.y), v3 = bf2f(u.y >> 16);
  float s1 = v0 + v1 + v2 + v3;
  float s2 = v0 * v0 + v1 * v1 + v2 * v2 + v3 * v3;
  #pragma unroll
  for (int off = 1; off < 64; off <<= 1) {
    s1 += __shfl_xor(s1, off);
    s2 += __shfl_xor(s2, off);
  }
  float m = s1 * (1.f / 256.f);
  float var = s2 * (1.f / 256.f) - m * m;
  float rs = rsqrtf(var + 1e-6f);
  int c = lane * 4;
  float4 w4 = *(const float4*)&lw[c];
  float4 b4 = *(const float4*)&lb[c];
  float o0 = (v0 - m) * rs * w4.x + b4.x;
  float o1 = (v1 - m) * rs * w4.y + b4.y;
  float o2 = (v2 - m) * rs * w4.z + b4.z;
  float o3 = (v3 - m) * rs * w4.w + b4.w;
  u32 a = (u32)f2bf(o0) | ((u32)f2bf(o1) << 16);
  u32 b = (u32)f2bf(o2) | ((u32)f2bf(o3) << 16);
  *(uint2*)&O[row * 256 + c] = make_uint2(a, b);
}

// ---------------- depthwise 3x3 over (H,W), layout (n,c) bf16 ----------------
__global__ __launch_bounds__(256)
void k_dw3x3(const u16* __restrict__ Y1, const float* __restrict__ dww,
             const float* __restrict__ dwb, u16* __restrict__ Yc) {
  int tid = threadIdx.x;
  int n = blockIdx.x * 4 + (tid >> 6);
  int c0 = (tid & 63) * 4;
  int b = n >> 12, hw = n & 4095, h = hw >> 6, w = hw & 63;
  float a0 = dwb[c0], a1 = dwb[c0 + 1], a2 = dwb[c0 + 2], a3 = dwb[c0 + 3];
  #pragma unroll
  for (int ky = 0; ky < 3; ++ky) {
    int hh = h + ky - 1;
    if (hh < 0 || hh > 63) continue;
    #pragma unroll
    for (int kx = 0; kx < 3; ++kx) {
      int ww = w + kx - 1;
      if (ww < 0 || ww > 63) continue;
      size_t nn = ((size_t)b << 12) + (hh << 6) + ww;
      uint2 u = *(const uint2*)&Y1[nn * 256 + c0];
      int widx = ky * 3 + kx;
      a0 += bf2f(u.x) * dww[(c0 + 0) * 9 + widx];
      a1 += bf2f(u.x >> 16) * dww[(c0 + 1) * 9 + widx];
      a2 += bf2f(u.y) * dww[(c0 + 2) * 9 + widx];
      a3 += bf2f(u.y >> 16) * dww[(c0 + 3) * 9 + widx];
    }
  }
  u32 p0 = (u32)f2bf(a0) | ((u32)f2bf(a1) << 16);
  u32 p1 = (u32)f2bf(a2) | ((u32)f2bf(a3) << 16);
  *(uint2*)&Yc[(size_t)n * 256 + c0] = make_uint2(p0, p1);
}

// ---------------- 4-direction conv1d sum: Z = (w0+w2)*4neigh + 4*w1*G --------
__global__ __launch_bounds__(256)
void k_scan(const u16* __restrict__ G, const float* __restrict__ dww,
            u16* __restrict__ Z) {
  int tid = threadIdx.x;
  int n = blockIdx.x * 2 + (tid >> 7);
  int c0 = (tid & 127) * 4;
  int b = n >> 12, hw = n & 4095, h = hw >> 6, w = hw & 63;
  int m = w * 64 + h;
  float s0 = 0.f, s1 = 0.f, s2 = 0.f, s3 = 0.f;
  auto addn = [&](int nn) {
    uint2 u = *(const uint2*)&G[(size_t)nn * 512 + c0];
    s0 += bf2f(u.x); s1 += bf2f(u.x >> 16);
    s2 += bf2f(u.y); s3 += bf2f(u.y >> 16);
  };
  if (hw > 0) addn(n - 1);
  if (hw < 4095) addn(n + 1);
  if (m > 0)   { int mm = m - 1; addn((b << 12) + ((mm & 63) << 6) + (mm >> 6)); }
  if (m < 4095){ int mm = m + 1; addn((b << 12) + ((mm & 63) << 6) + (mm >> 6)); }
  uint2 uc = *(const uint2*)&G[(size_t)n * 512 + c0];
  float g0 = bf2f(uc.x), g1 = bf2f(uc.x >> 16), g2 = bf2f(uc.y), g3 = bf2f(uc.y >> 16);
  float w00 = dww[(c0 + 0) * 3], w01 = dww[(c0 + 0) * 3 + 1], w02 = dww[(c0 + 0) * 3 + 2];
  float w10 = dww[(c0 + 1) * 3], w11 = dww[(c0 + 1) * 3 + 1], w12 = dww[(c0 + 1) * 3 + 2];
  float w20 = dww[(c0 + 2) * 3], w21 = dww[(c0 + 2) * 3 + 1], w22 = dww[(c0 + 2) * 3 + 2];
  float w30 = dww[(c0 + 3) * 3], w31 = dww[(c0 + 3) * 3 + 1], w32 = dww[(c0 + 3) * 3 + 2];
  float z0 = (w00 + w02) * s0 + 4.f * w01 * g0;
  float z1 = (w10 + w12) * s1 + 4.f * w11 * g1;
  float z2 = (w20 + w22) * s2 + 4.f * w21 * g2;
  float z3 = (w30 + w32) * s3 + 4.f * w31 * g3;
  u32 p0 = (u32)f2bf(z0) | ((u32)f2bf(z1) << 16);
  u32 p1 = (u32)f2bf(z2) | ((u32)f2bf(z3) << 16);
  *(uint2*)&Z[(size_t)n * 512 + c0] = make_uint2(p0, p1);
}

// ---------------- MFMA GEMM: C[n,o] = A[n,:]·W[o,:], 128x128 tile, BK=32 ------
// EPI 0: outb[n*ldo+o] = bf16(acc + bias[o])
// EPI 1: outb[n*256+o] = bf16(0.25*acc + bias[o] + resb[n*256+o])
// EPI 2: swapped operands (D rows = o); outf[(b*256+o)*4096+hw] = acc + bias[o] + resf[idx]
template <int EPI>
__global__ __launch_bounds__(256, 2)
void k_gemm(const u16* __restrict__ A, const u16* __restrict__ W,
            const float* __restrict__ bias, int K, int nTo, int ldo,
            u16* __restrict__ outb, const u16* __restrict__ resb,
            float* __restrict__ outf, const float* __restrict__ resf) {
  __shared__ u16 tA[128 * 32];
  __shared__ u16 tW[128 * 32];
  int tid = threadIdx.x;
  int tn = blockIdx.x / nTo, to = blockIdx.x % nTo;
  int n0 = tn * 128, o0 = to * 128;
  int lane = tid & 63, wv = tid >> 6;
  int wr = wv >> 1, wc = wv & 1;
  int fr = lane & 15, kc = lane >> 4;
  int srow = lane >> 2, scol = (lane & 3) * 8;
  f32x4 acc[4][4] = {};
  int nK = K >> 5;
  for (int kt = 0; kt < nK; ++kt) {
    int k0 = kt * 32;
    #pragma unroll
    for (int pass = 0; pass < 2; ++pass) {
      int rowblk = wv * 32 + pass * 16;
      gload16(A + (size_t)(n0 + rowblk + srow) * K + k0 + scol, &tA[rowblk * 32]);
      gload16(W + (size_t)(o0 + rowblk + srow) * K + k0 + scol, &tW[rowblk * 32]);
    }
    __syncthreads();
    const u16* fa = (EPI == 2) ? tW : tA;
    const u16* fb = (EPI == 2) ? tA : tW;
    bf16x8 af[4], wf[4];
    #pragma unroll
    for (int m = 0; m < 4; ++m)
      af[m] = *(const bf16x8*)&fa[(wr * 64 + m * 16 + fr) * 32 + kc * 8];
    #pragma unroll
    for (int n = 0; n < 4; ++n)
      wf[n] = *(const bf16x8*)&fb[(wc * 64 + n * 16 + fr) * 32 + kc * 8];
    #pragma unroll
    for (int m = 0; m < 4; ++m)
      #pragma unroll
      for (int n = 0; n < 4; ++n)
        acc[m][n] = __builtin_amdgcn_mfma_f32_16x16x32_bf16(af[m], wf[n], acc[m][n], 0, 0, 0);
    __syncthreads();
  }
  #pragma unroll
  for (int m = 0; m < 4; ++m) {
    #pragma unroll
    for (int n = 0; n < 4; ++n) {
      #pragma unroll
      for (int r = 0; r < 4; ++r) {
        float v = acc[m][n][r];
        if (EPI == 0) {
          int gn = n0 + wr * 64 + m * 16 + kc * 4 + r;
          int go = o0 + wc * 64 + n * 16 + fr;
          outb[(size_t)gn * ldo + go] = f2bf(v + bias[go]);
        } else if (EPI == 1) {
          int gn = n0 + wr * 64 + m * 16 + kc * 4 + r;
          int go = o0 + wc * 64 + n * 16 + fr;
          float val = 0.25f * v + bias[go] + bf2f(resb[(size_t)gn * 256 + go]);
          outb[(size_t)gn * 256 + go] = f2bf(val);
        } else {
          int go = o0 + wr * 64 + m * 16 + kc * 4 + r;
          int gn = n0 + wc * 64 + n * 16 + fr;
          int b = gn >> 12, hw = gn & 4095;
          size_t idx = (((size_t)(b * 256 + go)) << 12) + hw;
          outf[idx] = v + bias[go] + resf[idx];
        }
      }
    }
  }
}

// ------- fused ssm_in GEMM + SiLU gate: G[n,o] = (A·Wa[o]+ba)·sigmoid(A·Wg[o]+bg)
__global__ __launch_bounds__(256, 2)
void k_gemm_gate(const u16* __restrict__ A, const u16* __restrict__ W,
                 const float* __restrict__ bias, u16* __restrict__ G) {
  __shared__ u16 tA[128 * 32];
  __shared__ u16 tWa[128 * 32];
  __shared__ u16 tWg[128 * 32];
  int tid = threadIdx.x;
  int tn = blockIdx.x >> 2, to = blockIdx.x & 3;
  int n0 = tn * 128, o0 = to * 128;
  int lane = tid & 63, wv = tid >> 6;
  int wr = wv >> 1, wc = wv & 1;
  int fr = lane & 15, kc = lane >> 4;
  int srow = lane >> 2, scol = (lane & 3) * 8;
  const int K = 256;
  f32x4 acca[4][4] = {}, accg[4][4] = {};
  for (int kt = 0; kt < 8; ++kt) {
    int k0 = kt * 32;
    #pragma unroll
    for (int pass = 0; pass < 2; ++pass) {
      int rowblk = wv * 32 + pass * 16;
      gload16(A + (size_t)(n0 + rowblk + srow) * K + k0 + scol, &tA[rowblk * 32]);
      gload16(W + (size_t)(o0 + rowblk + srow) * K + k0 + scol, &tWa[rowblk * 32]);
      gload16(W + (size_t)(512 + o0 + rowblk + srow) * K + k0 + scol, &tWg[rowblk * 32]);
    }
    __syncthreads();
    bf16x8 af[4];
    #pragma unroll
    for (int m = 0; m < 4; ++m)
      af[m] = *(const bf16x8*)&tA[(wr * 64 + m * 16 + fr) * 32 + kc * 8];
    #pragma unroll
    for (int n = 0; n < 4; ++n) {
      bf16x8 wfa = *(const bf16x8*)&tWa[(wc * 64 + n * 16 + fr) * 32 + kc * 8];
      #pragma unroll
      for (int m = 0; m < 4; ++m)
        acca[m][n] = __builtin_amdgcn_mfma_f32_16x16x32_bf16(af[m], wfa, acca[m][n], 0, 0, 0);
      bf16x8 wfg = *(const bf16x8*)&tWg[(wc * 64 + n * 16 + fr) * 32 + kc * 8];
      #pragma unroll
      for (int m = 0; m < 4; ++m)
        accg[m][n] = __builtin_amdgcn_mfma_f32_16x16x32_bf16(af[m], wfg, accg[m][n], 0, 0, 0);
    }
    __syncthreads();
  }
  #pragma unroll
  for (int m = 0; m < 4; ++m) {
    #pragma unroll
    for (int n = 0; n < 4; ++n) {
      #pragma unroll
      for (int r = 0; r < 4; ++r) {
        int gn = n0 + wr * 64 + m * 16 + kc * 4 + r;
        int go = o0 + wc * 64 + n * 16 + fr;
        float a = acca[m][n][r] + bias[go];
        float g = accg[m][n][r] + bias[512 + go];
        float val = a / (1.f + expf(-g));
        G[(size_t)gn * 512 + go] = f2bf(val);
      }
    }
  }
}

extern "C" void kernel_launch(void* const* d_in, const int* in_sizes, int n_in,
                              void* d_out, int out_size, void* d_ws, size_t ws_size,
                              hipStream_t stream) {
  const float* x         = (const float*)d_in[0];
  const float* ln2d_w    = (const float*)d_in[1];
  const float* ln2d_b    = (const float*)d_in[2];
  const float* inproj_w  = (const float*)d_in[3];
  const float* inproj_b  = (const float*)d_in[4];
  const float* dw2d_w    = (const float*)d_in[5];
  const float* dw2d_b    = (const float*)d_in[6];
  const float* ssm_ln_w  = (const float*)d_in[7];
  const float* ssm_ln_b  = (const float*)d_in[8];
  const float* ssm_in_w  = (const float*)d_in[9];
  const float* ssm_in_b  = (const float*)d_in[10];
  const float* ssm_dw_w  = (const float*)d_in[11];
  const float* ssm_dw_b  = (const float*)d_in[12];
  const float* ssm_out_w = (const float*)d_in[13];
  const float* ssm_out_b = (const float*)d_in[14];
  const float* outproj_w = (const float*)d_in[15];
  const float* outproj_b = (const float*)d_in[16];
  float* out = (float*)d_out;

  char* ws = (char*)d_ws;
  size_t off = 0;
  auto take = [&](size_t bytes) -> char* {
    char* p = ws + off;
    off = (off + bytes + 255) & ~(size_t)255;
    return p;
  };
  u16* w1b   = (u16*)take(65536 * 2);
  u16* w2b   = (u16*)take(262144 * 2);
  u16* w3b   = (u16*)take(131072 * 2);
  u16* w4b   = (u16*)take(65536 * 2);
  float* cvec= (float*)take(256 * 4);
  u16* Abuf  = (u16*)take((size_t)16384 * 256 * 2); // A1 -> A2 -> M (serial reuse)
  u16* Y1    = (u16*)take((size_t)16384 * 256 * 2);
  u16* Yc    = (u16*)take((size_t)16384 * 256 * 2);
  u16* G     = (u16*)take((size_t)16384 * 512 * 2);
  u16* Z     = (u16*)take((size_t)16384 * 512 * 2);
  (void)ws_size; (void)in_sizes; (void)n_in; (void)out_size;

  k_tobf16<<<64, 256, 0, stream>>>(inproj_w, w1b, 65536);
  k_tobf16<<<256, 256, 0, stream>>>(ssm_in_w, w2b, 262144);
  k_tobf16<<<128, 256, 0, stream>>>(ssm_out_w, w3b, 131072);
  k_tobf16<<<64, 256, 0, stream>>>(outproj_w, w4b, 65536);
  k_cvec<<<1, 256, 0, stream>>>(ssm_out_w, ssm_dw_b, ssm_out_b, cvec);

  // 1) LN over channels + transpose to (n,c)
  k_ln2d<<<256, 256, 0, stream>>>(x, ln2d_w, ln2d_b, Abuf);
  // 2) inproj GEMM
  k_gemm<0><<<256, 256, 0, stream>>>(Abuf, w1b, inproj_b, 256, 2, 256, Y1, nullptr, nullptr, nullptr);
  // 3) depthwise 3x3
  k_dw3x3<<<4096, 256, 0, stream>>>(Y1, dw2d_w, dw2d_b, Yc);
  // 4) ssm LN
  k_lnrow<<<4096, 256, 0, stream>>>(Yc, ssm_ln_w, ssm_ln_b, Abuf);
  // 5) ssm_in GEMM + SiLU gate (fused, no R materialization)
  k_gemm_gate<<<512, 256, 0, stream>>>(Abuf, w2b, ssm_in_b, G);
  // 6) 4-direction conv1d sum
  k_scan<<<8192, 256, 0, stream>>>(G, ssm_dw_w, Z);
  // 7) ssm_out GEMM: M = 0.25*Z@Wout^T + cvec + Yc
  k_gemm<1><<<256, 256, 0, stream>>>(Z, w3b, cvec, 512, 2, 256, Abuf, Yc, nullptr, nullptr);
  // 8) outproj GEMM (transposed store to BCHW) + x residual
  k_gemm<2><<<256, 256, 0, stream>>>(Abuf, w4b, outproj_b, 256, 2, 256, nullptr, nullptr, out, x);
}

// Round 2
// 130.771 us; speedup vs baseline: 1.2186x; 1.2186x over previous
//
#include <hip/hip_runtime.h>

typedef float f32x4 __attribute__((ext_vector_type(4)));
typedef __bf16 bf16x8 __attribute__((ext_vector_type(8)));
typedef unsigned short u16;
typedef unsigned int u32;

__device__ __forceinline__ float bf2f(u32 bits16) {
  u32 x = (bits16 & 0xffffu) << 16;
  return __builtin_bit_cast(float, x);
}
__device__ __forceinline__ u16 f2bf(float f) {
  u32 x = __builtin_bit_cast(u32, f);
  x += 0x7fffu + ((x >> 16) & 1u);
  return (u16)(x >> 16);
}
__device__ __forceinline__ void gload16(const void* g, void* l) {
  __builtin_amdgcn_global_load_lds((__attribute__((address_space(1))) void*)g,
                                   (__attribute__((address_space(3))) void*)l,
                                   16, 0, 0);
}

// ---------------- f32 -> bf16 convert (weights) ----------------
__global__ __launch_bounds__(256) void k_tobf16(const float* __restrict__ s,
                                                u16* __restrict__ d, int n) {
  int i = (blockIdx.x * 256 + threadIdx.x) * 4;
  if (i + 3 < n) {
    float4 v = *(const float4*)&s[i];
    u32 a = (u32)f2bf(v.x) | ((u32)f2bf(v.y) << 16);
    u32 b = (u32)f2bf(v.z) | ((u32)f2bf(v.w) << 16);
    *(uint2*)&d[i] = make_uint2(a, b);
  }
}

// cvec[o] = ssm_dw_b @ ssm_out_w[o,:] + ssm_out_b[o]
__global__ __launch_bounds__(256) void k_cvec(const float* __restrict__ Wout,
                                              const float* __restrict__ dwb,
                                              const float* __restrict__ outb,
                                              float* __restrict__ cvec) {
  int o = threadIdx.x;
  float s = outb[o];
  for (int k = 0; k < 512; ++k) s += dwb[k] * Wout[o * 512 + k];
  cvec[o] = s;
}

// transpose dw2d weights [256][9] -> [9][256]
__global__ __launch_bounds__(256) void k_dwT(const float* __restrict__ dww,
                                             float* __restrict__ wT) {
  int c = threadIdx.x;
  #pragma unroll
  for (int j = 0; j < 9; ++j) wT[j * 256 + c] = dww[c * 9 + j];
}

// scan weight prep: w02[c]=w0+w2, w14[c]=4*w1  (c in [0,512))
__global__ __launch_bounds__(512) void k_scanw(const float* __restrict__ dww,
                                               float* __restrict__ w02,
                                               float* __restrict__ w14) {
  int c = threadIdx.x;
  w02[c] = dww[c * 3 + 0] + dww[c * 3 + 2];
  w14[c] = 4.f * dww[c * 3 + 1];
}

// ---------------- LN over channels of BCHW + transpose to (n,c) bf16 ----------
__global__ __launch_bounds__(256)
void k_ln2d(const float* __restrict__ x, const float* __restrict__ lw,
            const float* __restrict__ lb, u16* __restrict__ A) {
  __shared__ float ps1[4][64], ps2[4][64];
  __shared__ float mu[64], rsd[64];
  __shared__ float T[64 * 67];
  int tid = threadIdx.x;
  int wv = tid >> 6, p = tid & 63;
  int n0 = blockIdx.x * 64;
  int bb = n0 >> 12;
  int hw0 = n0 & 4095;
  const float* xb = x + ((size_t)bb << 20);
  float s1 = 0.f, s2 = 0.f;
  for (int i = 0; i < 64; ++i) {
    int c = wv * 64 + i;
    float v = xb[((size_t)c << 12) + hw0 + p];
    s1 += v; s2 += v * v;
  }
  ps1[wv][p] = s1; ps2[wv][p] = s2;
  __syncthreads();
  if (tid < 64) {
    float S1 = ps1[0][tid] + ps1[1][tid] + ps1[2][tid] + ps1[3][tid];
    float S2 = ps2[0][tid] + ps2[1][tid] + ps2[2][tid] + ps2[3][tid];
    float m = S1 * (1.f / 256.f);
    float var = S2 * (1.f / 256.f) - m * m;
    mu[tid] = m;
    rsd[tid] = rsqrtf(var + 1e-6f);
  }
  __syncthreads();
  for (int cc = 0; cc < 4; ++cc) {
    #pragma unroll
    for (int i = 0; i < 16; ++i) {
      int cl = i * 4 + wv;
      int c = cc * 64 + cl;
      float v = xb[((size_t)c << 12) + hw0 + p];
      T[cl * 67 + p] = (v - mu[p]) * rsd[p] * lw[c] + lb[c];
    }
    __syncthreads();
    int p2b = tid >> 4, c4 = (tid & 15) * 4;
    #pragma unroll
    for (int i2 = 0; i2 < 4; ++i2) {
      int p2 = p2b + 16 * i2;
      u32 a = (u32)f2bf(T[(c4 + 0) * 67 + p2]) | ((u32)f2bf(T[(c4 + 1) * 67 + p2]) << 16);
      u32 b = (u32)f2bf(T[(c4 + 2) * 67 + p2]) | ((u32)f2bf(T[(c4 + 3) * 67 + p2]) << 16);
      *(uint2*)&A[(size_t)(n0 + p2) * 256 + cc * 64 + c4] = make_uint2(a, b);
    }
    __syncthreads();
  }
}

// -------- depthwise 3x3 + fused row-LN: Yc = conv(Y1), A = LN(Yc) ----------
__global__ __launch_bounds__(256)
void k_dw3x3_ln(const u16* __restrict__ Y1, const float* __restrict__ wT,
                const float* __restrict__ dwb, const float* __restrict__ lnw,
                const float* __restrict__ lnb, u16* __restrict__ Yc,
                u16* __restrict__ A) {
  int tid = threadIdx.x;
  int n = blockIdx.x * 4 + (tid >> 6);
  int lane = tid & 63;
  int c0 = lane * 4;
  int b = n >> 12, hw = n & 4095, h = hw >> 6, w = hw & 63;
  float4 b4 = *(const float4*)&dwb[c0];
  float a0 = b4.x, a1 = b4.y, a2 = b4.z, a3 = b4.w;
  #pragma unroll
  for (int ky = 0; ky < 3; ++ky) {
    int hh = h + ky - 1;
    if (hh < 0 || hh > 63) continue;
    #pragma unroll
    for (int kx = 0; kx < 3; ++kx) {
      int ww = w + kx - 1;
      if (ww < 0 || ww > 63) continue;
      size_t nn = ((size_t)b << 12) + (hh << 6) + ww;
      uint2 u = *(const uint2*)&Y1[nn * 256 + c0];
      float4 w4 = *(const float4*)&wT[(ky * 3 + kx) * 256 + c0];
      a0 += bf2f(u.x) * w4.x;
      a1 += bf2f(u.x >> 16) * w4.y;
      a2 += bf2f(u.y) * w4.z;
      a3 += bf2f(u.y >> 16) * w4.w;
    }
  }
  u32 p0 = (u32)f2bf(a0) | ((u32)f2bf(a1) << 16);
  u32 p1 = (u32)f2bf(a2) | ((u32)f2bf(a3) << 16);
  *(uint2*)&Yc[(size_t)n * 256 + c0] = make_uint2(p0, p1);
  // fused row LN across the wave (wave holds the full 256-channel row)
  float s1 = a0 + a1 + a2 + a3;
  float s2 = a0 * a0 + a1 * a1 + a2 * a2 + a3 * a3;
  #pragma unroll
  for (int off = 1; off < 64; off <<= 1) {
    s1 += __shfl_xor(s1, off);
    s2 += __shfl_xor(s2, off);
  }
  float m = s1 * (1.f / 256.f);
  float var = s2 * (1.f / 256.f) - m * m;
  float rs = rsqrtf(var + 1e-6f);
  float4 w4 = *(const float4*)&lnw[c0];
  float4 g4 = *(const float4*)&lnb[c0];
  float o0 = (a0 - m) * rs * w4.x + g4.x;
  float o1 = (a1 - m) * rs * w4.y + g4.y;
  float o2 = (a2 - m) * rs * w4.z + g4.z;
  float o3 = (a3 - m) * rs * w4.w + g4.w;
  u32 q0 = (u32)f2bf(o0) | ((u32)f2bf(o1) << 16);
  u32 q1 = (u32)f2bf(o2) | ((u32)f2bf(o3) << 16);
  *(uint2*)&A[(size_t)n * 256 + c0] = make_uint2(q0, q1);
}

// ---------------- 4-direction conv1d sum: Z = w02*4neigh + w14*G --------
__global__ __launch_bounds__(256)
void k_scan(const u16* __restrict__ G, const float* __restrict__ w02,
            const float* __restrict__ w14, u16* __restrict__ Z) {
  int tid = threadIdx.x;
  int n = blockIdx.x * 2 + (tid >> 7);
  int c0 = (tid & 127) * 4;
  int b = n >> 12, hw = n & 4095, h = hw >> 6, w = hw & 63;
  int m = w * 64 + h;
  float s0 = 0.f, s1 = 0.f, s2 = 0.f, s3 = 0.f;
  auto addn = [&](int nn) {
    uint2 u = *(const uint2*)&G[(size_t)nn * 512 + c0];
    s0 += bf2f(u.x); s1 += bf2f(u.x >> 16);
    s2 += bf2f(u.y); s3 += bf2f(u.y >> 16);
  };
  if (hw > 0) addn(n - 1);
  if (hw < 4095) addn(n + 1);
  if (m > 0)   { int mm = m - 1; addn((b << 12) + ((mm & 63) << 6) + (mm >> 6)); }
  if (m < 4095){ int mm = m + 1; addn((b << 12) + ((mm & 63) << 6) + (mm >> 6)); }
  uint2 uc = *(const uint2*)&G[(size_t)n * 512 + c0];
  float g0 = bf2f(uc.x), g1 = bf2f(uc.x >> 16), g2 = bf2f(uc.y), g3 = bf2f(uc.y >> 16);
  float4 wa = *(const float4*)&w02[c0];
  float4 wb = *(const float4*)&w14[c0];
  float z0 = wa.x * s0 + wb.x * g0;
  float z1 = wa.y * s1 + wb.y * g1;
  float z2 = wa.z * s2 + wb.z * g2;
  float z3 = wa.w * s3 + wb.w * g3;
  u32 p0 = (u32)f2bf(z0) | ((u32)f2bf(z1) << 16);
  u32 p1 = (u32)f2bf(z2) | ((u32)f2bf(z3) << 16);
  *(uint2*)&Z[(size_t)n * 512 + c0] = make_uint2(p0, p1);
}

// ---------------- MFMA GEMM: C[n,o] = A[n,:]·W[o,:], 128x128 tile, BK=32 ------
// EPI 0: outb[n*ldo+o] = bf16(acc + bias[o])
// EPI 1: outb[n*256+o] = bf16(0.25*acc + bias[o] + resb[n*256+o])
// EPI 2: swapped operands (D rows = o); outf[(b*256+o)*4096+hw] = acc + bias[o] + resf[idx]
template <int EPI>
__global__ __launch_bounds__(256, 2)
void k_gemm(const u16* __restrict__ A, const u16* __restrict__ W,
            const float* __restrict__ bias, int K, int nTo, int ldo,
            u16* __restrict__ outb, const u16* __restrict__ resb,
            float* __restrict__ outf, const float* __restrict__ resf) {
  __shared__ u16 tA[128 * 32];
  __shared__ u16 tW[128 * 32];
  int tid = threadIdx.x;
  int tn = blockIdx.x / nTo, to = blockIdx.x % nTo;
  int n0 = tn * 128, o0 = to * 128;
  int lane = tid & 63, wv = tid >> 6;
  int wr = wv >> 1, wc = wv & 1;
  int fr = lane & 15, kc = lane >> 4;
  int srow = lane >> 2, scol = (lane & 3) * 8;
  f32x4 acc[4][4] = {};
  int nK = K >> 5;
  for (int kt = 0; kt < nK; ++kt) {
    int k0 = kt * 32;
    #pragma unroll
    for (int pass = 0; pass < 2; ++pass) {
      int rowblk = wv * 32 + pass * 16;
      gload16(A + (size_t)(n0 + rowblk + srow) * K + k0 + scol, &tA[rowblk * 32]);
      gload16(W + (size_t)(o0 + rowblk + srow) * K + k0 + scol, &tW[rowblk * 32]);
    }
    __syncthreads();
    const u16* fa = (EPI == 2) ? tW : tA;
    const u16* fb = (EPI == 2) ? tA : tW;
    bf16x8 af[4], wf[4];
    #pragma unroll
    for (int m = 0; m < 4; ++m)
      af[m] = *(const bf16x8*)&fa[(wr * 64 + m * 16 + fr) * 32 + kc * 8];
    #pragma unroll
    for (int n = 0; n < 4; ++n)
      wf[n] = *(const bf16x8*)&fb[(wc * 64 + n * 16 + fr) * 32 + kc * 8];
    #pragma unroll
    for (int m = 0; m < 4; ++m)
      #pragma unroll
      for (int n = 0; n < 4; ++n)
        acc[m][n] = __builtin_amdgcn_mfma_f32_16x16x32_bf16(af[m], wf[n], acc[m][n], 0, 0, 0);
    __syncthreads();
  }
  #pragma unroll
  for (int m = 0; m < 4; ++m) {
    #pragma unroll
    for (int n = 0; n < 4; ++n) {
      #pragma unroll
      for (int r = 0; r < 4; ++r) {
        float v = acc[m][n][r];
        if (EPI == 0) {
          int gn = n0 + wr * 64 + m * 16 + kc * 4 + r;
          int go = o0 + wc * 64 + n * 16 + fr;
          outb[(size_t)gn * ldo + go] = f2bf(v + bias[go]);
        } else if (EPI == 1) {
          int gn = n0 + wr * 64 + m * 16 + kc * 4 + r;
          int go = o0 + wc * 64 + n * 16 + fr;
          float val = 0.25f * v + bias[go] + bf2f(resb[(size_t)gn * 256 + go]);
          outb[(size_t)gn * 256 + go] = f2bf(val);
        } else {
          int go = o0 + wr * 64 + m * 16 + kc * 4 + r;
          int gn = n0 + wc * 64 + n * 16 + fr;
          int b = gn >> 12, hw = gn & 4095;
          size_t idx = (((size_t)(b * 256 + go)) << 12) + hw;
          outf[idx] = v + bias[go] + resf[idx];
        }
      }
    }
  }
}

// ------- fused ssm_in GEMM + SiLU gate: G[n,o] = (A·Wa[o]+ba)·sigmoid(A·Wg[o]+bg)
__global__ __launch_bounds__(256, 2)
void k_gemm_gate(const u16* __restrict__ A, const u16* __restrict__ W,
                 const float* __restrict__ bias, u16* __restrict__ G) {
  __shared__ u16 tA[128 * 32];
  __shared__ u16 tWa[128 * 32];
  __shared__ u16 tWg[128 * 32];
  int tid = threadIdx.x;
  int tn = blockIdx.x >> 2, to = blockIdx.x & 3;
  int n0 = tn * 128, o0 = to * 128;
  int lane = tid & 63, wv = tid >> 6;
  int wr = wv >> 1, wc = wv & 1;
  int fr = lane & 15, kc = lane >> 4;
  int srow = lane >> 2, scol = (lane & 3) * 8;
  const int K = 256;
  f32x4 acca[4][4] = {}, accg[4][4] = {};
  for (int kt = 0; kt < 8; ++kt) {
    int k0 = kt * 32;
    #pragma unroll
    for (int pass = 0; pass < 2; ++pass) {
      int rowblk = wv * 32 + pass * 16;
      gload16(A + (size_t)(n0 + rowblk + srow) * K + k0 + scol, &tA[rowblk * 32]);
      gload16(W + (size_t)(o0 + rowblk + srow) * K + k0 + scol, &tWa[rowblk * 32]);
      gload16(W + (size_t)(512 + o0 + rowblk + srow) * K + k0 + scol, &tWg[rowblk * 32]);
    }
    __syncthreads();
    bf16x8 af[4];
    #pragma unroll
    for (int m = 0; m < 4; ++m)
      af[m] = *(const bf16x8*)&tA[(wr * 64 + m * 16 + fr) * 32 + kc * 8];
    #pragma unroll
    for (int n = 0; n < 4; ++n) {
      bf16x8 wfa = *(const bf16x8*)&tWa[(wc * 64 + n * 16 + fr) * 32 + kc * 8];
      #pragma unroll
      for (int m = 0; m < 4; ++m)
        acca[m][n] = __builtin_amdgcn_mfma_f32_16x16x32_bf16(af[m], wfa, acca[m][n], 0, 0, 0);
      bf16x8 wfg = *(const bf16x8*)&tWg[(wc * 64 + n * 16 + fr) * 32 + kc * 8];
      #pragma unroll
      for (int m = 0; m < 4; ++m)
        accg[m][n] = __builtin_amdgcn_mfma_f32_16x16x32_bf16(af[m], wfg, accg[m][n], 0, 0, 0);
    }
    __syncthreads();
  }
  #pragma unroll
  for (int m = 0; m < 4; ++m) {
    #pragma unroll
    for (int n = 0; n < 4; ++n) {
      #pragma unroll
      for (int r = 0; r < 4; ++r) {
        int gn = n0 + wr * 64 + m * 16 + kc * 4 + r;
        int go = o0 + wc * 64 + n * 16 + fr;
        float a = acca[m][n][r] + bias[go];
        float g = accg[m][n][r] + bias[512 + go];
        float val = a / (1.f + expf(-g));
        G[(size_t)gn * 512 + go] = f2bf(val);
      }
    }
  }
}

extern "C" void kernel_launch(void* const* d_in, const int* in_sizes, int n_in,
                              void* d_out, int out_size, void* d_ws, size_t ws_size,
                              hipStream_t stream) {
  const float* x         = (const float*)d_in[0];
  const float* ln2d_w    = (const float*)d_in[1];
  const float* ln2d_b    = (const float*)d_in[2];
  const float* inproj_w  = (const float*)d_in[3];
  const float* inproj_b  = (const float*)d_in[4];
  const float* dw2d_w    = (const float*)d_in[5];
  const float* dw2d_b    = (const float*)d_in[6];
  const float* ssm_ln_w  = (const float*)d_in[7];
  const float* ssm_ln_b  = (const float*)d_in[8];
  const float* ssm_in_w  = (const float*)d_in[9];
  const float* ssm_in_b  = (const float*)d_in[10];
  const float* ssm_dw_w  = (const float*)d_in[11];
  const float* ssm_dw_b  = (const float*)d_in[12];
  const float* ssm_out_w = (const float*)d_in[13];
  const float* ssm_out_b = (const float*)d_in[14];
  const float* outproj_w = (const float*)d_in[15];
  const float* outproj_b = (const float*)d_in[16];
  float* out = (float*)d_out;

  char* ws = (char*)d_ws;
  size_t off = 0;
  auto take = [&](size_t bytes) -> char* {
    char* p = ws + off;
    off = (off + bytes + 255) & ~(size_t)255;
    return p;
  };
  u16* w1b   = (u16*)take(65536 * 2);
  u16* w2b   = (u16*)take(262144 * 2);
  u16* w3b   = (u16*)take(131072 * 2);
  u16* w4b   = (u16*)take(65536 * 2);
  float* cvec= (float*)take(256 * 4);
  float* wT9 = (float*)take(9 * 256 * 4);
  float* w02 = (float*)take(512 * 4);
  float* w14 = (float*)take(512 * 4);
  u16* Abuf  = (u16*)take((size_t)16384 * 256 * 2); // A1 -> A2 -> M (serial reuse)
  u16* Y1    = (u16*)take((size_t)16384 * 256 * 2);
  u16* Yc    = (u16*)take((size_t)16384 * 256 * 2);
  u16* G     = (u16*)take((size_t)16384 * 512 * 2);
  u16* Z     = (u16*)take((size_t)16384 * 512 * 2);
  (void)ws_size; (void)in_sizes; (void)n_in; (void)out_size;

  k_tobf16<<<64, 256, 0, stream>>>(inproj_w, w1b, 65536);
  k_tobf16<<<256, 256, 0, stream>>>(ssm_in_w, w2b, 262144);
  k_tobf16<<<128, 256, 0, stream>>>(ssm_out_w, w3b, 131072);
  k_tobf16<<<64, 256, 0, stream>>>(outproj_w, w4b, 65536);
  k_cvec<<<1, 256, 0, stream>>>(ssm_out_w, ssm_dw_b, ssm_out_b, cvec);
  k_dwT<<<1, 256, 0, stream>>>(dw2d_w, wT9);
  k_scanw<<<1, 512, 0, stream>>>(ssm_dw_w, w02, w14);

  // 1) LN over channels + transpose to (n,c)
  k_ln2d<<<256, 256, 0, stream>>>(x, ln2d_w, ln2d_b, Abuf);
  // 2) inproj GEMM
  k_gemm<0><<<256, 256, 0, stream>>>(Abuf, w1b, inproj_b, 256, 2, 256, Y1, nullptr, nullptr, nullptr);
  // 3) depthwise 3x3 + fused ssm LN
  k_dw3x3_ln<<<4096, 256, 0, stream>>>(Y1, wT9, dw2d_b, ssm_ln_w, ssm_ln_b, Yc, Abuf);
  // 4) ssm_in GEMM + SiLU gate (fused, no R materialization)
  k_gemm_gate<<<512, 256, 0, stream>>>(Abuf, w2b, ssm_in_b, G);
  // 5) 4-direction conv1d sum
  k_scan<<<8192, 256, 0, stream>>>(G, w02, w14, Z);
  // 6) ssm_out GEMM: M = 0.25*Z@Wout^T + cvec + Yc
  k_gemm<1><<<256, 256, 0, stream>>>(Z, w3b, cvec, 512, 2, 256, Abuf, Yc, nullptr, nullptr);
  // 7) outproj GEMM (transposed store to BCHW) + x residual
  k_gemm<2><<<256, 256, 0, stream>>>(Abuf, w4b, outproj_b, 256, 2, 256, nullptr, nullptr, out, x);
}

// Round 3
// 112.969 us; speedup vs baseline: 1.4106x; 1.1576x over previous
//
#include <hip/hip_runtime.h>

typedef float f32x4 __attribute__((ext_vector_type(4)));
typedef __bf16 bf16x8 __attribute__((ext_vector_type(8)));
typedef unsigned short u16;
typedef unsigned int u32;

__device__ __forceinline__ float bf2f(u32 b) {
  u32 x = (b & 0xffffu) << 16;
  return __builtin_bit_cast(float, x);
}
__device__ __forceinline__ u16 f2bf(float f) {
  u32 x = __builtin_bit_cast(u32, f);
  x += 0x7fffu + ((x >> 16) & 1u);
  return (u16)(x >> 16);
}
__device__ __forceinline__ void gload16(const void* g, void* l) {
  __builtin_amdgcn_global_load_lds((__attribute__((address_space(1))) void*)g,
                                   (__attribute__((address_space(3))) void*)l,
                                   16, 0, 0);
}

// ---------------- one-shot prep: weight bf16 conversion + small folds --------
__global__ __launch_bounds__(256)
void k_prep(const float* __restrict__ inproj_w, const float* __restrict__ ssm_in_w,
            const float* __restrict__ ssm_out_w, const float* __restrict__ outproj_w,
            const float* __restrict__ dw2d_w, const float* __restrict__ ssm_dw_w,
            const float* __restrict__ ssm_dw_b, const float* __restrict__ ssm_out_b,
            u16* __restrict__ w1b, u16* __restrict__ w2b, u16* __restrict__ w3b,
            u16* __restrict__ w4b, float* __restrict__ cvec, float* __restrict__ wT9,
            float* __restrict__ w02, float* __restrict__ w14) {
  int bid = blockIdx.x, tid = threadIdx.x;
  if (bid < 512) {
    const float* s; u16* d; int base;
    if (bid < 256)      { s = ssm_in_w;  d = w2b; base = bid; }
    else if (bid < 384) { s = ssm_out_w; d = w3b; base = bid - 256; }
    else if (bid < 448) { s = inproj_w;  d = w1b; base = bid - 384; }
    else                { s = outproj_w; d = w4b; base = bid - 448; }
    int i = base * 1024 + tid * 4;
    float4 v = *(const float4*)&s[i];
    u32 a = (u32)f2bf(v.x) | ((u32)f2bf(v.y) << 16);
    u32 b = (u32)f2bf(v.z) | ((u32)f2bf(v.w) << 16);
    *(uint2*)&d[i] = make_uint2(a, b);
  } else if (bid == 512) {
    // cvec[o] = ssm_dw_b @ ssm_out_w[o,:] + ssm_out_b[o]
    float s = ssm_out_b[tid];
    const float* wr = ssm_out_w + (size_t)tid * 512;
    #pragma unroll 8
    for (int k = 0; k < 512; ++k) s += ssm_dw_b[k] * wr[k];
    cvec[tid] = s;
  } else {
    #pragma unroll
    for (int j = 0; j < 9; ++j) wT9[j * 256 + tid] = dw2d_w[tid * 9 + j];
    #pragma unroll
    for (int q = 0; q < 2; ++q) {
      int c = tid + q * 256;
      w02[c] = ssm_dw_w[c * 3 + 0] + ssm_dw_w[c * 3 + 2];
      w14[c] = 4.f * ssm_dw_w[c * 3 + 1];
    }
  }
}

// ---------------- LN over channels of BCHW + transpose to (n,c) bf16 ----------
// Single HBM pass: tile cached in LDS (stride-65 pad -> 2-way conflicts only).
__global__ __launch_bounds__(256, 2)
void k_ln2d(const float* __restrict__ x, const float* __restrict__ lw,
            const float* __restrict__ lb, u16* __restrict__ A) {
  __shared__ float T[256 * 65];
  __shared__ float ps1[4][64], ps2[4][64];
  __shared__ float mu[64], rsd[64];
  int tid = threadIdx.x, wv = tid >> 6, lane = tid & 63;
  int cq = lane >> 4, p4 = (lane & 15) * 4;
  int n0 = blockIdx.x * 64, bb = n0 >> 12, hw0 = n0 & 4095;
  const float* xb = x + ((size_t)bb << 20);
  float s0 = 0, s1 = 0, s2 = 0, s3 = 0;
  float q0 = 0, q1 = 0, q2 = 0, q3 = 0;
  #pragma unroll 4
  for (int i = 0; i < 16; ++i) {
    int c = wv * 64 + i * 4 + cq;
    float4 v = *(const float4*)&xb[((size_t)c << 12) + hw0 + p4];
    T[c * 65 + p4 + 0] = v.x; T[c * 65 + p4 + 1] = v.y;
    T[c * 65 + p4 + 2] = v.z; T[c * 65 + p4 + 3] = v.w;
    s0 += v.x; s1 += v.y; s2 += v.z; s3 += v.w;
    q0 += v.x * v.x; q1 += v.y * v.y; q2 += v.z * v.z; q3 += v.w * v.w;
  }
  #pragma unroll
  for (int off = 16; off < 64; off <<= 1) {
    s0 += __shfl_xor(s0, off); s1 += __shfl_xor(s1, off);
    s2 += __shfl_xor(s2, off); s3 += __shfl_xor(s3, off);
    q0 += __shfl_xor(q0, off); q1 += __shfl_xor(q1, off);
    q2 += __shfl_xor(q2, off); q3 += __shfl_xor(q3, off);
  }
  if (cq == 0) {
    ps1[wv][p4 + 0] = s0; ps1[wv][p4 + 1] = s1; ps1[wv][p4 + 2] = s2; ps1[wv][p4 + 3] = s3;
    ps2[wv][p4 + 0] = q0; ps2[wv][p4 + 1] = q1; ps2[wv][p4 + 2] = q2; ps2[wv][p4 + 3] = q3;
  }
  __syncthreads();
  if (tid < 64) {
    float S1 = ps1[0][tid] + ps1[1][tid] + ps1[2][tid] + ps1[3][tid];
    float S2 = ps2[0][tid] + ps2[1][tid] + ps2[2][tid] + ps2[3][tid];
    float m = S1 * (1.f / 256.f);
    float var = S2 * (1.f / 256.f) - m * m;
    mu[tid] = m;
    rsd[tid] = rsqrtf(var + 1e-6f);
  }
  __syncthreads();
  int c4b = (tid & 15) * 4, p2b = tid >> 4;
  #pragma unroll
  for (int cc = 0; cc < 4; ++cc) {
    int c4 = cc * 64 + c4b;
    float4 w4 = *(const float4*)&lw[c4];
    float4 g4 = *(const float4*)&lb[c4];
    #pragma unroll
    for (int i2 = 0; i2 < 4; ++i2) {
      int p2 = p2b + 16 * i2;
      float m = mu[p2], rs = rsd[p2];
      float o0 = (T[(c4 + 0) * 65 + p2] - m) * rs * w4.x + g4.x;
      float o1 = (T[(c4 + 1) * 65 + p2] - m) * rs * w4.y + g4.y;
      float o2 = (T[(c4 + 2) * 65 + p2] - m) * rs * w4.z + g4.z;
      float o3 = (T[(c4 + 3) * 65 + p2] - m) * rs * w4.w + g4.w;
      u32 a = (u32)f2bf(o0) | ((u32)f2bf(o1) << 16);
      u32 b = (u32)f2bf(o2) | ((u32)f2bf(o3) << 16);
      *(uint2*)&A[(size_t)(n0 + p2) * 256 + c4] = make_uint2(a, b);
    }
  }
}

// -------- depthwise 3x3 + fused row-LN: Yc = conv(Y1), A = LN(Yc) ----------
__global__ __launch_bounds__(256)
void k_dw3x3_ln(const u16* __restrict__ Y1, const float* __restrict__ wT,
                const float* __restrict__ dwb, const float* __restrict__ lnw,
                const float* __restrict__ lnb, u16* __restrict__ Yc,
                u16* __restrict__ A) {
  int tid = threadIdx.x;
  int n = blockIdx.x * 4 + (tid >> 6);
  int lane = tid & 63;
  int c0 = lane * 4;
  int b = n >> 12, hw = n & 4095, h = hw >> 6, w = hw & 63;
  float4 b4 = *(const float4*)&dwb[c0];
  float a0 = b4.x, a1 = b4.y, a2 = b4.z, a3 = b4.w;
  #pragma unroll
  for (int ky = 0; ky < 3; ++ky) {
    int hh = h + ky - 1;
    if (hh < 0 || hh > 63) continue;
    #pragma unroll
    for (int kx = 0; kx < 3; ++kx) {
      int ww = w + kx - 1;
      if (ww < 0 || ww > 63) continue;
      size_t nn = ((size_t)b << 12) + (hh << 6) + ww;
      uint2 u = *(const uint2*)&Y1[nn * 256 + c0];
      float4 w4 = *(const float4*)&wT[(ky * 3 + kx) * 256 + c0];
      a0 += bf2f(u.x) * w4.x;
      a1 += bf2f(u.x >> 16) * w4.y;
      a2 += bf2f(u.y) * w4.z;
      a3 += bf2f(u.y >> 16) * w4.w;
    }
  }
  u32 p0 = (u32)f2bf(a0) | ((u32)f2bf(a1) << 16);
  u32 p1 = (u32)f2bf(a2) | ((u32)f2bf(a3) << 16);
  *(uint2*)&Yc[(size_t)n * 256 + c0] = make_uint2(p0, p1);
  float s1 = a0 + a1 + a2 + a3;
  float s2 = a0 * a0 + a1 * a1 + a2 * a2 + a3 * a3;
  #pragma unroll
  for (int off = 1; off < 64; off <<= 1) {
    s1 += __shfl_xor(s1, off);
    s2 += __shfl_xor(s2, off);
  }
  float m = s1 * (1.f / 256.f);
  float var = s2 * (1.f / 256.f) - m * m;
  float rs = rsqrtf(var + 1e-6f);
  float4 w4 = *(const float4*)&lnw[c0];
  float4 g4 = *(const float4*)&lnb[c0];
  float o0 = (a0 - m) * rs * w4.x + g4.x;
  float o1 = (a1 - m) * rs * w4.y + g4.y;
  float o2 = (a2 - m) * rs * w4.z + g4.z;
  float o3 = (a3 - m) * rs * w4.w + g4.w;
  u32 qa = (u32)f2bf(o0) | ((u32)f2bf(o1) << 16);
  u32 qb = (u32)f2bf(o2) | ((u32)f2bf(o3) << 16);
  *(uint2*)&A[(size_t)n * 256 + c0] = make_uint2(qa, qb);
}

// ---------------- 4-direction conv1d sum: Z = w02*4neigh + w14*G --------
__global__ __launch_bounds__(256)
void k_scan(const u16* __restrict__ G, const float* __restrict__ w02,
            const float* __restrict__ w14, u16* __restrict__ Z) {
  int tid = threadIdx.x;
  int n = blockIdx.x * 2 + (tid >> 7);
  int c0 = (tid & 127) * 4;
  int b = n >> 12, hw = n & 4095, h = hw >> 6, w = hw & 63;
  int m = w * 64 + h;
  float s0 = 0.f, s1 = 0.f, s2 = 0.f, s3 = 0.f;
  auto addn = [&](int nn) {
    uint2 u = *(const uint2*)&G[(size_t)nn * 512 + c0];
    s0 += bf2f(u.x); s1 += bf2f(u.x >> 16);
    s2 += bf2f(u.y); s3 += bf2f(u.y >> 16);
  };
  if (hw > 0) addn(n - 1);
  if (hw < 4095) addn(n + 1);
  if (m > 0)    { int mm = m - 1; addn((b << 12) + ((mm & 63) << 6) + (mm >> 6)); }
  if (m < 4095) { int mm = m + 1; addn((b << 12) + ((mm & 63) << 6) + (mm >> 6)); }
  uint2 uc = *(const uint2*)&G[(size_t)n * 512 + c0];
  float g0 = bf2f(uc.x), g1 = bf2f(uc.x >> 16), g2 = bf2f(uc.y), g3 = bf2f(uc.y >> 16);
  float4 wa = *(const float4*)&w02[c0];
  float4 wb = *(const float4*)&w14[c0];
  float z0 = wa.x * s0 + wb.x * g0;
  float z1 = wa.y * s1 + wb.y * g1;
  float z2 = wa.z * s2 + wb.z * g2;
  float z3 = wa.w * s3 + wb.w * g3;
  u32 p0 = (u32)f2bf(z0) | ((u32)f2bf(z1) << 16);
  u32 p1 = (u32)f2bf(z2) | ((u32)f2bf(z3) << 16);
  *(uint2*)&Z[(size_t)n * 512 + c0] = make_uint2(p0, p1);
}

// ------- MFMA GEMM, 64x128 tile, BK=32, 2-phase double-buffered pipeline -----
// D[r][c] = R[r,:].C[c,:] (both row-major [rows][K]).  4 waves = 4 col-quarters.
// EPI 0: outb[r*ldo+c] = bf16(acc + bias[c])                      (R=A, C=W)
// EPI 1: outb[r*256+c] = bf16(0.25*acc + bias[c] + resb[r*256+c]) (R=Z, C=W)
// EPI 2: R=W (rows=o), C=A (cols=n); outf[(b*256+o)*4096+hw] = acc+bias[o]+resf
template <int EPI>
__global__ __launch_bounds__(256, 4)
void k_gemm2(const u16* __restrict__ R, const u16* __restrict__ Cm,
             const float* __restrict__ bias, int K, int nCt, int ldo,
             u16* __restrict__ outb, const u16* __restrict__ resb,
             float* __restrict__ outf, const float* __restrict__ resf) {
  __shared__ u16 tR[2][64 * 32];
  __shared__ u16 tC[2][128 * 32];
  int tid = threadIdx.x, lane = tid & 63, wv = tid >> 6;
  int rt = blockIdx.x / nCt, ct = blockIdx.x % nCt;
  int r0 = rt * 64, c0 = ct * 128;
  int fr = lane & 15, kc = lane >> 4;
  int sr = lane >> 2, sc = (lane & 3) * 8;
  f32x4 acc[4][2] = {};
  int nK = K >> 5;
  const u16* gR  = R  + (size_t)(r0 + wv * 16 + sr) * K + sc;
  const u16* gC0 = Cm + (size_t)(c0 + wv * 32 + sr) * K + sc;
  const u16* gC1 = Cm + (size_t)(c0 + wv * 32 + 16 + sr) * K + sc;
  auto STAGE = [&](int buf, int kt) {
    int k0 = kt * 32;
    gload16(gR + k0,  &tR[buf][wv * 16 * 32]);
    gload16(gC0 + k0, &tC[buf][(wv * 32) * 32]);
    gload16(gC1 + k0, &tC[buf][(wv * 32 + 16) * 32]);
  };
  auto COMPUTE = [&](int buf) {
    bf16x8 af[4], wf[2];
    #pragma unroll
    for (int m = 0; m < 4; ++m)
      af[m] = *(const bf16x8*)&tR[buf][(m * 16 + fr) * 32 + kc * 8];
    #pragma unroll
    for (int n = 0; n < 2; ++n)
      wf[n] = *(const bf16x8*)&tC[buf][(wv * 32 + n * 16 + fr) * 32 + kc * 8];
    #pragma unroll
    for (int m = 0; m < 4; ++m)
      #pragma unroll
      for (int n = 0; n < 2; ++n)
        acc[m][n] = __builtin_amdgcn_mfma_f32_16x16x32_bf16(af[m], wf[n], acc[m][n], 0, 0, 0);
  };
  STAGE(0, 0);
  __syncthreads();
  int cur = 0;
  for (int kt = 0; kt < nK - 1; ++kt) {
    STAGE(cur ^ 1, kt + 1);
    __builtin_amdgcn_sched_barrier(0);
    COMPUTE(cur);
    __syncthreads();
    cur ^= 1;
  }
  COMPUTE(cur);
  #pragma unroll
  for (int m = 0; m < 4; ++m) {
    #pragma unroll
    for (int n = 0; n < 2; ++n) {
      #pragma unroll
      for (int r = 0; r < 4; ++r) {
        float v = acc[m][n][r];
        if (EPI == 0) {
          int gn = r0 + m * 16 + kc * 4 + r;
          int go = c0 + wv * 32 + n * 16 + fr;
          outb[(size_t)gn * ldo + go] = f2bf(v + bias[go]);
        } else if (EPI == 1) {
          int gn = r0 + m * 16 + kc * 4 + r;
          int go = c0 + wv * 32 + n * 16 + fr;
          outb[(size_t)gn * 256 + go] =
              f2bf(0.25f * v + bias[go] + bf2f(resb[(size_t)gn * 256 + go]));
        } else {
          int go = r0 + m * 16 + kc * 4 + r;           // output channel
          int gn = c0 + wv * 32 + n * 16 + fr;         // position
          int b = gn >> 12, hw = gn & 4095;
          size_t idx = (((size_t)(b * 256 + go)) << 12) + hw;
          outf[idx] = v + bias[go] + resf[idx];
        }
      }
    }
  }
}

// ------- fused ssm_in GEMM + SiLU gate, same 2-phase structure --------------
__global__ __launch_bounds__(256, 3)
void k_gate2(const u16* __restrict__ A, const u16* __restrict__ W,
             const float* __restrict__ bias, u16* __restrict__ G) {
  __shared__ u16 tR[2][64 * 32];
  __shared__ u16 tCa[2][128 * 32];
  __shared__ u16 tCg[2][128 * 32];
  int tid = threadIdx.x, lane = tid & 63, wv = tid >> 6;
  int rt = blockIdx.x >> 2, ot = blockIdx.x & 3;
  int r0 = rt * 64, o0 = ot * 128;
  int fr = lane & 15, kc = lane >> 4;
  int sr = lane >> 2, sc = (lane & 3) * 8;
  const int K = 256;
  f32x4 acca[4][2] = {}, accg[4][2] = {};
  const u16* gR  = A + (size_t)(r0 + wv * 16 + sr) * K + sc;
  const u16* gA0 = W + (size_t)(o0 + wv * 32 + sr) * K + sc;
  const u16* gA1 = W + (size_t)(o0 + wv * 32 + 16 + sr) * K + sc;
  const u16* gG0 = W + (size_t)(512 + o0 + wv * 32 + sr) * K + sc;
  const u16* gG1 = W + (size_t)(512 + o0 + wv * 32 + 16 + sr) * K + sc;
  auto STAGE = [&](int buf, int kt) {
    int k0 = kt * 32;
    gload16(gR + k0,  &tR[buf][wv * 16 * 32]);
    gload16(gA0 + k0, &tCa[buf][(wv * 32) * 32]);
    gload16(gA1 + k0, &tCa[buf][(wv * 32 + 16) * 32]);
    gload16(gG0 + k0, &tCg[buf][(wv * 32) * 32]);
    gload16(gG1 + k0, &tCg[buf][(wv * 32 + 16) * 32]);
  };
  auto COMPUTE = [&](int buf) {
    bf16x8 af[4], wa[2], wg[2];
    #pragma unroll
    for (int m = 0; m < 4; ++m)
      af[m] = *(const bf16x8*)&tR[buf][(m * 16 + fr) * 32 + kc * 8];
    #pragma unroll
    for (int n = 0; n < 2; ++n) {
      wa[n] = *(const bf16x8*)&tCa[buf][(wv * 32 + n * 16 + fr) * 32 + kc * 8];
      wg[n] = *(const bf16x8*)&tCg[buf][(wv * 32 + n * 16 + fr) * 32 + kc * 8];
    }
    #pragma unroll
    for (int m = 0; m < 4; ++m)
      #pragma unroll
      for (int n = 0; n < 2; ++n) {
        acca[m][n] = __builtin_amdgcn_mfma_f32_16x16x32_bf16(af[m], wa[n], acca[m][n], 0, 0, 0);
        accg[m][n] = __builtin_amdgcn_mfma_f32_16x16x32_bf16(af[m], wg[n], accg[m][n], 0, 0, 0);
      }
  };
  STAGE(0, 0);
  __syncthreads();
  int cur = 0;
  for (int kt = 0; kt < 7; ++kt) {
    STAGE(cur ^ 1, kt + 1);
    __builtin_amdgcn_sched_barrier(0);
    COMPUTE(cur);
    __syncthreads();
    cur ^= 1;
  }
  COMPUTE(cur);
  #pragma unroll
  for (int m = 0; m < 4; ++m) {
    #pragma unroll
    for (int n = 0; n < 2; ++n) {
      #pragma unroll
      for (int r = 0; r < 4; ++r) {
        int gn = r0 + m * 16 + kc * 4 + r;
        int go = o0 + wv * 32 + n * 16 + fr;
        float a = acca[m][n][r] + bias[go];
        float g = accg[m][n][r] + bias[512 + go];
        G[(size_t)gn * 512 + go] = f2bf(a / (1.f + expf(-g)));
      }
    }
  }
}

extern "C" void kernel_launch(void* const* d_in, const int* in_sizes, int n_in,
                              void* d_out, int out_size, void* d_ws, size_t ws_size,
                              hipStream_t stream) {
  const float* x         = (const float*)d_in[0];
  const float* ln2d_w    = (const float*)d_in[1];
  const float* ln2d_b    = (const float*)d_in[2];
  const float* inproj_w  = (const float*)d_in[3];
  const float* inproj_b  = (const float*)d_in[4];
  const float* dw2d_w    = (const float*)d_in[5];
  const float* dw2d_b    = (const float*)d_in[6];
  const float* ssm_ln_w  = (const float*)d_in[7];
  const float* ssm_ln_b  = (const float*)d_in[8];
  const float* ssm_in_w  = (const float*)d_in[9];
  const float* ssm_in_b  = (const float*)d_in[10];
  const float* ssm_dw_w  = (const float*)d_in[11];
  const float* ssm_dw_b  = (const float*)d_in[12];
  const float* ssm_out_w = (const float*)d_in[13];
  const float* ssm_out_b = (const float*)d_in[14];
  const float* outproj_w = (const float*)d_in[15];
  const float* outproj_b = (const float*)d_in[16];
  float* out = (float*)d_out;

  char* ws = (char*)d_ws;
  size_t off = 0;
  auto take = [&](size_t bytes) -> char* {
    char* p = ws + off;
    off = (off + bytes + 255) & ~(size_t)255;
    return p;
  };
  u16* w1b    = (u16*)take(65536 * 2);
  u16* w2b    = (u16*)take(262144 * 2);
  u16* w3b    = (u16*)take(131072 * 2);
  u16* w4b    = (u16*)take(65536 * 2);
  float* cvec = (float*)take(256 * 4);
  float* wT9  = (float*)take(9 * 256 * 4);
  float* w02  = (float*)take(512 * 4);
  float* w14  = (float*)take(512 * 4);
  u16* Abuf   = (u16*)take((size_t)16384 * 256 * 2); // A1 -> A2 -> M (serial reuse)
  u16* Y1     = (u16*)take((size_t)16384 * 256 * 2);
  u16* Yc     = (u16*)take((size_t)16384 * 256 * 2);
  u16* G      = (u16*)take((size_t)16384 * 512 * 2);
  u16* Z      = (u16*)take((size_t)16384 * 512 * 2);
  (void)ws_size; (void)in_sizes; (void)n_in; (void)out_size;

  k_prep<<<514, 256, 0, stream>>>(inproj_w, ssm_in_w, ssm_out_w, outproj_w,
                                  dw2d_w, ssm_dw_w, ssm_dw_b, ssm_out_b,
                                  w1b, w2b, w3b, w4b, cvec, wT9, w02, w14);
  // 1) LN over channels + transpose to (n,c)
  k_ln2d<<<256, 256, 0, stream>>>(x, ln2d_w, ln2d_b, Abuf);
  // 2) inproj GEMM
  k_gemm2<0><<<512, 256, 0, stream>>>(Abuf, w1b, inproj_b, 256, 2, 256,
                                      Y1, nullptr, nullptr, nullptr);
  // 3) depthwise 3x3 + fused ssm LN
  k_dw3x3_ln<<<4096, 256, 0, stream>>>(Y1, wT9, dw2d_b, ssm_ln_w, ssm_ln_b, Yc, Abuf);
  // 4) ssm_in GEMM + SiLU gate
  k_gate2<<<1024, 256, 0, stream>>>(Abuf, w2b, ssm_in_b, G);
  // 5) 4-direction conv1d sum
  k_scan<<<8192, 256, 0, stream>>>(G, w02, w14, Z);
  // 6) ssm_out GEMM: M = 0.25*Z@Wout^T + cvec + Yc
  k_gemm2<1><<<512, 256, 0, stream>>>(Z, w3b, cvec, 512, 2, 256,
                                      Abuf, Yc, nullptr, nullptr);
  // 7) outproj GEMM (o-rows staged, position-cols) + x residual, f32 out
  k_gemm2<2><<<512, 256, 0, stream>>>(w4b, Abuf, outproj_b, 256, 128, 0,
                                      nullptr, nullptr, out, x);
}

// Round 4
// 105.665 us; speedup vs baseline: 1.5082x; 1.0691x over previous
//
#include <hip/hip_runtime.h>

typedef float f32x4 __attribute__((ext_vector_type(4)));
typedef __bf16 bf16x8 __attribute__((ext_vector_type(8)));
typedef unsigned short u16;
typedef unsigned int u32;

__device__ __forceinline__ float bf2f(u32 b) {
  u32 x = (b & 0xffffu) << 16;
  return __builtin_bit_cast(float, x);
}
__device__ __forceinline__ u16 f2bf(float f) {
  u32 x = __builtin_bit_cast(u32, f);
  x += 0x7fffu + ((x >> 16) & 1u);
  return (u16)(x >> 16);
}
__device__ __forceinline__ void gload16(const void* g, void* l) {
  __builtin_amdgcn_global_load_lds((__attribute__((address_space(1))) void*)g,
                                   (__attribute__((address_space(3))) void*)l,
                                   16, 0, 0);
}

// ---- LN over channels of BCHW + transpose to (n,c) bf16, + fused prep ------
// Blocks 0..255: LN (single HBM pass, tile in LDS).  Blocks 256..767: weight
// f32->bf16 conversion.  Block 768: cvec fold.  Block 769: dw-weight folds.
__global__ __launch_bounds__(256, 2)
void k_ln2d_prep(const float* __restrict__ x, const float* __restrict__ lw,
                 const float* __restrict__ lb, u16* __restrict__ A,
                 const float* __restrict__ inproj_w, const float* __restrict__ ssm_in_w,
                 const float* __restrict__ ssm_out_w, const float* __restrict__ outproj_w,
                 const float* __restrict__ dw2d_w, const float* __restrict__ ssm_dw_w,
                 const float* __restrict__ ssm_dw_b, const float* __restrict__ ssm_out_b,
                 u16* __restrict__ w1b, u16* __restrict__ w2b, u16* __restrict__ w3b,
                 u16* __restrict__ w4b, float* __restrict__ cvec, float* __restrict__ wT9,
                 float* __restrict__ w02, float* __restrict__ w14) {
  __shared__ float T[256 * 65];
  __shared__ float ps1[4][64], ps2[4][64];
  __shared__ float mu[64], rsd[64];
  int bid = blockIdx.x, tid = threadIdx.x;
  if (bid >= 256) {
    int pb = bid - 256;
    if (pb < 512) {
      const float* s; u16* d; int base;
      if (pb < 256)      { s = ssm_in_w;  d = w2b; base = pb; }
      else if (pb < 384) { s = ssm_out_w; d = w3b; base = pb - 256; }
      else if (pb < 448) { s = inproj_w;  d = w1b; base = pb - 384; }
      else               { s = outproj_w; d = w4b; base = pb - 448; }
      int i = base * 1024 + tid * 4;
      float4 v = *(const float4*)&s[i];
      u32 a = (u32)f2bf(v.x) | ((u32)f2bf(v.y) << 16);
      u32 b = (u32)f2bf(v.z) | ((u32)f2bf(v.w) << 16);
      *(uint2*)&d[i] = make_uint2(a, b);
    } else if (pb == 512) {
      float s = ssm_out_b[tid];
      const float* wr = ssm_out_w + (size_t)tid * 512;
      #pragma unroll 8
      for (int k = 0; k < 512; ++k) s += ssm_dw_b[k] * wr[k];
      cvec[tid] = s;
    } else {
      #pragma unroll
      for (int j = 0; j < 9; ++j) wT9[j * 256 + tid] = dw2d_w[tid * 9 + j];
      #pragma unroll
      for (int q = 0; q < 2; ++q) {
        int c = tid + q * 256;
        w02[c] = ssm_dw_w[c * 3 + 0] + ssm_dw_w[c * 3 + 2];
        w14[c] = 4.f * ssm_dw_w[c * 3 + 1];
      }
    }
    return;
  }
  int wv = tid >> 6, lane = tid & 63;
  int cq = lane >> 4, p4 = (lane & 15) * 4;
  int n0 = bid * 64, bb = n0 >> 12, hw0 = n0 & 4095;
  const float* xb = x + ((size_t)bb << 20);
  float s0 = 0, s1 = 0, s2 = 0, s3 = 0;
  float q0 = 0, q1 = 0, q2 = 0, q3 = 0;
  #pragma unroll 4
  for (int i = 0; i < 16; ++i) {
    int c = wv * 64 + i * 4 + cq;
    float4 v = *(const float4*)&xb[((size_t)c << 12) + hw0 + p4];
    T[c * 65 + p4 + 0] = v.x; T[c * 65 + p4 + 1] = v.y;
    T[c * 65 + p4 + 2] = v.z; T[c * 65 + p4 + 3] = v.w;
    s0 += v.x; s1 += v.y; s2 += v.z; s3 += v.w;
    q0 += v.x * v.x; q1 += v.y * v.y; q2 += v.z * v.z; q3 += v.w * v.w;
  }
  #pragma unroll
  for (int off = 16; off < 64; off <<= 1) {
    s0 += __shfl_xor(s0, off); s1 += __shfl_xor(s1, off);
    s2 += __shfl_xor(s2, off); s3 += __shfl_xor(s3, off);
    q0 += __shfl_xor(q0, off); q1 += __shfl_xor(q1, off);
    q2 += __shfl_xor(q2, off); q3 += __shfl_xor(q3, off);
  }
  if (cq == 0) {
    ps1[wv][p4 + 0] = s0; ps1[wv][p4 + 1] = s1; ps1[wv][p4 + 2] = s2; ps1[wv][p4 + 3] = s3;
    ps2[wv][p4 + 0] = q0; ps2[wv][p4 + 1] = q1; ps2[wv][p4 + 2] = q2; ps2[wv][p4 + 3] = q3;
  }
  __syncthreads();
  if (tid < 64) {
    float S1 = ps1[0][tid] + ps1[1][tid] + ps1[2][tid] + ps1[3][tid];
    float S2 = ps2[0][tid] + ps2[1][tid] + ps2[2][tid] + ps2[3][tid];
    float m = S1 * (1.f / 256.f);
    float var = S2 * (1.f / 256.f) - m * m;
    mu[tid] = m;
    rsd[tid] = rsqrtf(var + 1e-6f);
  }
  __syncthreads();
  int c4b = (tid & 15) * 4, p2b = tid >> 4;
  #pragma unroll
  for (int cc = 0; cc < 4; ++cc) {
    int c4 = cc * 64 + c4b;
    float4 w4 = *(const float4*)&lw[c4];
    float4 g4 = *(const float4*)&lb[c4];
    #pragma unroll
    for (int i2 = 0; i2 < 4; ++i2) {
      int p2 = p2b + 16 * i2;
      float m = mu[p2], rs = rsd[p2];
      float o0 = (T[(c4 + 0) * 65 + p2] - m) * rs * w4.x + g4.x;
      float o1 = (T[(c4 + 1) * 65 + p2] - m) * rs * w4.y + g4.y;
      float o2 = (T[(c4 + 2) * 65 + p2] - m) * rs * w4.z + g4.z;
      float o3 = (T[(c4 + 3) * 65 + p2] - m) * rs * w4.w + g4.w;
      u32 a = (u32)f2bf(o0) | ((u32)f2bf(o1) << 16);
      u32 b = (u32)f2bf(o2) | ((u32)f2bf(o3) << 16);
      *(uint2*)&A[(size_t)(n0 + p2) * 256 + c4] = make_uint2(a, b);
    }
  }
}

// -------- depthwise 3x3 + fused row-LN: Yc = conv(Y1), A = LN(Yc) ----------
__global__ __launch_bounds__(256)
void k_dw3x3_ln(const u16* __restrict__ Y1, const float* __restrict__ wT,
                const float* __restrict__ dwb, const float* __restrict__ lnw,
                const float* __restrict__ lnb, u16* __restrict__ Yc,
                u16* __restrict__ A) {
  int tid = threadIdx.x;
  int n = blockIdx.x * 4 + (tid >> 6);
  int lane = tid & 63;
  int c0 = lane * 4;
  int b = n >> 12, hw = n & 4095, h = hw >> 6, w = hw & 63;
  float4 b4 = *(const float4*)&dwb[c0];
  float a0 = b4.x, a1 = b4.y, a2 = b4.z, a3 = b4.w;
  #pragma unroll
  for (int ky = 0; ky < 3; ++ky) {
    int hh = h + ky - 1;
    if (hh < 0 || hh > 63) continue;
    #pragma unroll
    for (int kx = 0; kx < 3; ++kx) {
      int ww = w + kx - 1;
      if (ww < 0 || ww > 63) continue;
      size_t nn = ((size_t)b << 12) + (hh << 6) + ww;
      uint2 u = *(const uint2*)&Y1[nn * 256 + c0];
      float4 w4 = *(const float4*)&wT[(ky * 3 + kx) * 256 + c0];
      a0 += bf2f(u.x) * w4.x;
      a1 += bf2f(u.x >> 16) * w4.y;
      a2 += bf2f(u.y) * w4.z;
      a3 += bf2f(u.y >> 16) * w4.w;
    }
  }
  u32 p0 = (u32)f2bf(a0) | ((u32)f2bf(a1) << 16);
  u32 p1 = (u32)f2bf(a2) | ((u32)f2bf(a3) << 16);
  *(uint2*)&Yc[(size_t)n * 256 + c0] = make_uint2(p0, p1);
  float s1 = a0 + a1 + a2 + a3;
  float s2 = a0 * a0 + a1 * a1 + a2 * a2 + a3 * a3;
  #pragma unroll
  for (int off = 1; off < 64; off <<= 1) {
    s1 += __shfl_xor(s1, off);
    s2 += __shfl_xor(s2, off);
  }
  float m = s1 * (1.f / 256.f);
  float var = s2 * (1.f / 256.f) - m * m;
  float rs = rsqrtf(var + 1e-6f);
  float4 w4 = *(const float4*)&lnw[c0];
  float4 g4 = *(const float4*)&lnb[c0];
  float o0 = (a0 - m) * rs * w4.x + g4.x;
  float o1 = (a1 - m) * rs * w4.y + g4.y;
  float o2 = (a2 - m) * rs * w4.z + g4.z;
  float o3 = (a3 - m) * rs * w4.w + g4.w;
  u32 qa = (u32)f2bf(o0) | ((u32)f2bf(o1) << 16);
  u32 qb = (u32)f2bf(o2) | ((u32)f2bf(o3) << 16);
  *(uint2*)&A[(size_t)n * 256 + c0] = make_uint2(qa, qb);
}

// ------- MFMA GEMM, 64x128 tile, BK=32, 2-phase double-buffered pipeline -----
// EPI 0: outb[r*ldo+c] = bf16(acc + bias[c])                      (R=A, C=W)
// EPI 2: R=W (rows=o), C=A (cols=n); outf[(b*256+o)*4096+hw] = acc+bias[o]+resf
template <int EPI>
__global__ __launch_bounds__(256, 4)
void k_gemm2(const u16* __restrict__ R, const u16* __restrict__ Cm,
             const float* __restrict__ bias, int K, int nCt, int ldo,
             u16* __restrict__ outb, float* __restrict__ outf,
             const float* __restrict__ resf) {
  __shared__ u16 tR[2][64 * 32];
  __shared__ u16 tC[2][128 * 32];
  int tid = threadIdx.x, lane = tid & 63, wv = tid >> 6;
  int rt = blockIdx.x / nCt, ct = blockIdx.x % nCt;
  int r0 = rt * 64, c0 = ct * 128;
  int fr = lane & 15, kc = lane >> 4;
  int sr = lane >> 2, sc = (lane & 3) * 8;
  f32x4 acc[4][2] = {};
  int nK = K >> 5;
  const u16* gR  = R  + (size_t)(r0 + wv * 16 + sr) * K + sc;
  const u16* gC0 = Cm + (size_t)(c0 + wv * 32 + sr) * K + sc;
  const u16* gC1 = Cm + (size_t)(c0 + wv * 32 + 16 + sr) * K + sc;
  auto STAGE = [&](int buf, int kt) {
    int k0 = kt * 32;
    gload16(gR + k0,  &tR[buf][wv * 16 * 32]);
    gload16(gC0 + k0, &tC[buf][(wv * 32) * 32]);
    gload16(gC1 + k0, &tC[buf][(wv * 32 + 16) * 32]);
  };
  auto COMPUTE = [&](int buf) {
    bf16x8 af[4], wf[2];
    #pragma unroll
    for (int m = 0; m < 4; ++m)
      af[m] = *(const bf16x8*)&tR[buf][(m * 16 + fr) * 32 + kc * 8];
    #pragma unroll
    for (int n = 0; n < 2; ++n)
      wf[n] = *(const bf16x8*)&tC[buf][(wv * 32 + n * 16 + fr) * 32 + kc * 8];
    #pragma unroll
    for (int m = 0; m < 4; ++m)
      #pragma unroll
      for (int n = 0; n < 2; ++n)
        acc[m][n] = __builtin_amdgcn_mfma_f32_16x16x32_bf16(af[m], wf[n], acc[m][n], 0, 0, 0);
  };
  STAGE(0, 0);
  __syncthreads();
  int cur = 0;
  for (int kt = 0; kt < nK - 1; ++kt) {
    STAGE(cur ^ 1, kt + 1);
    __builtin_amdgcn_sched_barrier(0);
    COMPUTE(cur);
    __syncthreads();
    cur ^= 1;
  }
  COMPUTE(cur);
  #pragma unroll
  for (int m = 0; m < 4; ++m) {
    #pragma unroll
    for (int n = 0; n < 2; ++n) {
      #pragma unroll
      for (int r = 0; r < 4; ++r) {
        float v = acc[m][n][r];
        if (EPI == 0) {
          int gn = r0 + m * 16 + kc * 4 + r;
          int go = c0 + wv * 32 + n * 16 + fr;
          outb[(size_t)gn * ldo + go] = f2bf(v + bias[go]);
        } else {
          int go = r0 + m * 16 + kc * 4 + r;           // output channel
          int gn = c0 + wv * 32 + n * 16 + fr;         // position
          int b = gn >> 12, hw = gn & 4095;
          size_t idx = (((size_t)(b * 256 + go)) << 12) + hw;
          outf[idx] = v + bias[go] + resf[idx];
        }
      }
    }
  }
}

// ------- fused ssm_in GEMM + SiLU gate, same 2-phase structure --------------
__global__ __launch_bounds__(256, 3)
void k_gate2(const u16* __restrict__ A, const u16* __restrict__ W,
             const float* __restrict__ bias, u16* __restrict__ G) {
  __shared__ u16 tR[2][64 * 32];
  __shared__ u16 tCa[2][128 * 32];
  __shared__ u16 tCg[2][128 * 32];
  int tid = threadIdx.x, lane = tid & 63, wv = tid >> 6;
  int rt = blockIdx.x >> 2, ot = blockIdx.x & 3;
  int r0 = rt * 64, o0 = ot * 128;
  int fr = lane & 15, kc = lane >> 4;
  int sr = lane >> 2, sc = (lane & 3) * 8;
  const int K = 256;
  f32x4 acca[4][2] = {}, accg[4][2] = {};
  const u16* gR  = A + (size_t)(r0 + wv * 16 + sr) * K + sc;
  const u16* gA0 = W + (size_t)(o0 + wv * 32 + sr) * K + sc;
  const u16* gA1 = W + (size_t)(o0 + wv * 32 + 16 + sr) * K + sc;
  const u16* gG0 = W + (size_t)(512 + o0 + wv * 32 + sr) * K + sc;
  const u16* gG1 = W + (size_t)(512 + o0 + wv * 32 + 16 + sr) * K + sc;
  auto STAGE = [&](int buf, int kt) {
    int k0 = kt * 32;
    gload16(gR + k0,  &tR[buf][wv * 16 * 32]);
    gload16(gA0 + k0, &tCa[buf][(wv * 32) * 32]);
    gload16(gA1 + k0, &tCa[buf][(wv * 32 + 16) * 32]);
    gload16(gG0 + k0, &tCg[buf][(wv * 32) * 32]);
    gload16(gG1 + k0, &tCg[buf][(wv * 32 + 16) * 32]);
  };
  auto COMPUTE = [&](int buf) {
    bf16x8 af[4], wa[2], wg[2];
    #pragma unroll
    for (int m = 0; m < 4; ++m)
      af[m] = *(const bf16x8*)&tR[buf][(m * 16 + fr) * 32 + kc * 8];
    #pragma unroll
    for (int n = 0; n < 2; ++n) {
      wa[n] = *(const bf16x8*)&tCa[buf][(wv * 32 + n * 16 + fr) * 32 + kc * 8];
      wg[n] = *(const bf16x8*)&tCg[buf][(wv * 32 + n * 16 + fr) * 32 + kc * 8];
    }
    #pragma unroll
    for (int m = 0; m < 4; ++m)
      #pragma unroll
      for (int n = 0; n < 2; ++n) {
        acca[m][n] = __builtin_amdgcn_mfma_f32_16x16x32_bf16(af[m], wa[n], acca[m][n], 0, 0, 0);
        accg[m][n] = __builtin_amdgcn_mfma_f32_16x16x32_bf16(af[m], wg[n], accg[m][n], 0, 0, 0);
      }
  };
  STAGE(0, 0);
  __syncthreads();
  int cur = 0;
  for (int kt = 0; kt < 7; ++kt) {
    STAGE(cur ^ 1, kt + 1);
    __builtin_amdgcn_sched_barrier(0);
    COMPUTE(cur);
    __syncthreads();
    cur ^= 1;
  }
  COMPUTE(cur);
  #pragma unroll
  for (int m = 0; m < 4; ++m) {
    #pragma unroll
    for (int n = 0; n < 2; ++n) {
      #pragma unroll
      for (int r = 0; r < 4; ++r) {
        int gn = r0 + m * 16 + kc * 4 + r;
        int go = o0 + wv * 32 + n * 16 + fr;
        float a = acca[m][n][r] + bias[go];
        float g = accg[m][n][r] + bias[512 + go];
        G[(size_t)gn * 512 + go] = f2bf(a / (1.f + expf(-g)));
      }
    }
  }
}

// ------- fused 4-dir conv1d + ssm_out GEMM -----------------------------------
// R rows = Z[n,k] computed on the fly from G (5-pt stencil); C = W3 (256x512).
// Tile 32 rows x 256 cols, grid 512, K=512 (16 steps of 32).
// M[n*256+o] = bf16(0.25*acc + cvec[o] + Yc[n*256+o])
__global__ __launch_bounds__(256, 2)
void k_gemm_scan(const u16* __restrict__ G, const u16* __restrict__ W3,
                 const float* __restrict__ w02, const float* __restrict__ w14,
                 const float* __restrict__ cvec, const u16* __restrict__ Yc,
                 u16* __restrict__ M) {
  __shared__ u16 tR[2][32 * 32];
  __shared__ u16 tC[2][256 * 32];
  int tid = threadIdx.x, lane = tid & 63, wv = tid >> 6;
  int r0 = blockIdx.x * 32;
  int fr = lane & 15, kc = lane >> 4;
  // Z-compute assignment: each thread owns 4 channels of one row.
  int zrow = tid >> 3;            // 0..31
  int zg = (tid & 7) * 4;         // channel-group within the 32-wide K slice
  int n = r0 + zrow;
  int b = n >> 12, hw = n & 4095, h = hw >> 6, w = hw & 63;
  int m = w * 64 + h;
  int mm1 = m - 1, mp1 = m + 1;
  size_t o_c = (size_t)n * 512 + zg;
  size_t o_p = (size_t)(hw > 0 ? n - 1 : n) * 512 + zg;
  size_t o_n = (size_t)(hw < 4095 ? n + 1 : n) * 512 + zg;
  size_t o_u = (size_t)(m > 0 ? ((b << 12) + ((mm1 & 63) << 6) + (mm1 >> 6)) : n) * 512 + zg;
  size_t o_d = (size_t)(m < 4095 ? ((b << 12) + ((mp1 & 63) << 6) + (mp1 >> 6)) : n) * 512 + zg;
  float mP = hw > 0 ? 1.f : 0.f, mN = hw < 4095 ? 1.f : 0.f;
  float mU = m > 0 ? 1.f : 0.f, mD = m < 4095 ? 1.f : 0.f;
  f32x4 acc[2][4] = {};
  auto STAGE_C = [&](int buf, int kt) {
    int k0 = kt * 32;
    #pragma unroll
    for (int i = 0; i < 4; ++i) {
      int s0 = wv * 256 + i * 64;        // wave-uniform lane-slot base
      int s = s0 + lane;
      int row = s >> 2, off = (s & 3) * 8;
      gload16(W3 + (size_t)row * 512 + k0 + off, &tC[buf][s0 * 8]);
    }
  };
  uint2 lc, lp, ln_, lu, ld;
  float4 va, vb;
  auto ZLOAD = [&](int kt) {
    int c = kt * 32 + zg;
    lc = *(const uint2*)&G[o_c + (kt * 32)];
    lp = *(const uint2*)&G[o_p + (kt * 32)];
    ln_ = *(const uint2*)&G[o_n + (kt * 32)];
    lu = *(const uint2*)&G[o_u + (kt * 32)];
    ld = *(const uint2*)&G[o_d + (kt * 32)];
    va = *(const float4*)&w02[c];
    vb = *(const float4*)&w14[c];
  };
  auto ZSTORE = [&](int buf) {
    float s_0 = mP * bf2f(lp.x) + mN * bf2f(ln_.x) + mU * bf2f(lu.x) + mD * bf2f(ld.x);
    float s_1 = mP * bf2f(lp.x >> 16) + mN * bf2f(ln_.x >> 16) + mU * bf2f(lu.x >> 16) + mD * bf2f(ld.x >> 16);
    float s_2 = mP * bf2f(lp.y) + mN * bf2f(ln_.y) + mU * bf2f(lu.y) + mD * bf2f(ld.y);
    float s_3 = mP * bf2f(lp.y >> 16) + mN * bf2f(ln_.y >> 16) + mU * bf2f(lu.y >> 16) + mD * bf2f(ld.y >> 16);
    float z0 = va.x * s_0 + vb.x * bf2f(lc.x);
    float z1 = va.y * s_1 + vb.y * bf2f(lc.x >> 16);
    float z2 = va.z * s_2 + vb.z * bf2f(lc.y);
    float z3 = va.w * s_3 + vb.w * bf2f(lc.y >> 16);
    u32 p0 = (u32)f2bf(z0) | ((u32)f2bf(z1) << 16);
    u32 p1 = (u32)f2bf(z2) | ((u32)f2bf(z3) << 16);
    *(uint2*)&tR[buf][zrow * 32 + zg] = make_uint2(p0, p1);
  };
  auto COMPUTE = [&](int buf) {
    bf16x8 af[2], wf[4];
    #pragma unroll
    for (int mi = 0; mi < 2; ++mi)
      af[mi] = *(const bf16x8*)&tR[buf][(mi * 16 + fr) * 32 + kc * 8];
    #pragma unroll
    for (int ni = 0; ni < 4; ++ni)
      wf[ni] = *(const bf16x8*)&tC[buf][(wv * 64 + ni * 16 + fr) * 32 + kc * 8];
    #pragma unroll
    for (int mi = 0; mi < 2; ++mi)
      #pragma unroll
      for (int ni = 0; ni < 4; ++ni)
        acc[mi][ni] = __builtin_amdgcn_mfma_f32_16x16x32_bf16(af[mi], wf[ni], acc[mi][ni], 0, 0, 0);
  };
  // prologue
  STAGE_C(0, 0);
  ZLOAD(0);
  ZSTORE(0);
  __syncthreads();
  int cur = 0;
  for (int kt = 0; kt < 15; ++kt) {
    ZLOAD(kt + 1);              // issue early (T14): hidden under MFMA
    STAGE_C(cur ^ 1, kt + 1);
    COMPUTE(cur);
    ZSTORE(cur ^ 1);            // vmcnt-wait lands after the MFMA cluster
    __syncthreads();
    cur ^= 1;
  }
  COMPUTE(cur);
  #pragma unroll
  for (int mi = 0; mi < 2; ++mi) {
    #pragma unroll
    for (int ni = 0; ni < 4; ++ni) {
      #pragma unroll
      for (int r = 0; r < 4; ++r) {
        int gn = r0 + mi * 16 + kc * 4 + r;
        int go = wv * 64 + ni * 16 + fr;
        size_t idx = (size_t)gn * 256 + go;
        M[idx] = f2bf(0.25f * acc[mi][ni][r] + cvec[go] + bf2f(Yc[idx]));
      }
    }
  }
}

extern "C" void kernel_launch(void* const* d_in, const int* in_sizes, int n_in,
                              void* d_out, int out_size, void* d_ws, size_t ws_size,
                              hipStream_t stream) {
  const float* x         = (const float*)d_in[0];
  const float* ln2d_w    = (const float*)d_in[1];
  const float* ln2d_b    = (const float*)d_in[2];
  const float* inproj_w  = (const float*)d_in[3];
  const float* inproj_b  = (const float*)d_in[4];
  const float* dw2d_w    = (const float*)d_in[5];
  const float* dw2d_b    = (const float*)d_in[6];
  const float* ssm_ln_w  = (const float*)d_in[7];
  const float* ssm_ln_b  = (const float*)d_in[8];
  const float* ssm_in_w  = (const float*)d_in[9];
  const float* ssm_in_b  = (const float*)d_in[10];
  const float* ssm_dw_w  = (const float*)d_in[11];
  const float* ssm_dw_b  = (const float*)d_in[12];
  const float* ssm_out_w = (const float*)d_in[13];
  const float* ssm_out_b = (const float*)d_in[14];
  const float* outproj_w = (const float*)d_in[15];
  const float* outproj_b = (const float*)d_in[16];
  float* out = (float*)d_out;

  char* ws = (char*)d_ws;
  size_t off = 0;
  auto take = [&](size_t bytes) -> char* {
    char* p = ws + off;
    off = (off + bytes + 255) & ~(size_t)255;
    return p;
  };
  u16* w1b    = (u16*)take(65536 * 2);
  u16* w2b    = (u16*)take(262144 * 2);
  u16* w3b    = (u16*)take(131072 * 2);
  u16* w4b    = (u16*)take(65536 * 2);
  float* cvec = (float*)take(256 * 4);
  float* wT9  = (float*)take(9 * 256 * 4);
  float* w02  = (float*)take(512 * 4);
  float* w14  = (float*)take(512 * 4);
  u16* Abuf   = (u16*)take((size_t)16384 * 256 * 2); // A1 -> A2 -> M (serial reuse)
  u16* Y1     = (u16*)take((size_t)16384 * 256 * 2);
  u16* Yc     = (u16*)take((size_t)16384 * 256 * 2);
  u16* G      = (u16*)take((size_t)16384 * 512 * 2);
  (void)ws_size; (void)in_sizes; (void)n_in; (void)out_size;

  // 1) LN over channels + transpose to (n,c); fused weight prep (extra blocks)
  k_ln2d_prep<<<770, 256, 0, stream>>>(x, ln2d_w, ln2d_b, Abuf,
                                       inproj_w, ssm_in_w, ssm_out_w, outproj_w,
                                       dw2d_w, ssm_dw_w, ssm_dw_b, ssm_out_b,
                                       w1b, w2b, w3b, w4b, cvec, wT9, w02, w14);
  // 2) inproj GEMM
  k_gemm2<0><<<512, 256, 0, stream>>>(Abuf, w1b, inproj_b, 256, 2, 256,
                                      Y1, nullptr, nullptr);
  // 3) depthwise 3x3 + fused ssm LN
  k_dw3x3_ln<<<4096, 256, 0, stream>>>(Y1, wT9, dw2d_b, ssm_ln_w, ssm_ln_b, Yc, Abuf);
  // 4) ssm_in GEMM + SiLU gate
  k_gate2<<<1024, 256, 0, stream>>>(Abuf, w2b, ssm_in_b, G);
  // 5) fused 4-dir conv1d + ssm_out GEMM: M = 0.25*Z@Wout^T + cvec + Yc
  k_gemm_scan<<<512, 256, 0, stream>>>(G, w3b, w02, w14, cvec, Yc, Abuf);
  // 6) outproj GEMM (o-rows staged, position-cols) + x residual, f32 out
  k_gemm2<2><<<512, 256, 0, stream>>>(w4b, Abuf, outproj_b, 256, 128, 0,
                                      nullptr, out, x);
}